// Round 16
// baseline (403.124 us; speedup 1.0000x reference)
//
#include <hip/hip_runtime.h>

#define N_NODES 50000
#define N_EDGES 800000
#define DIM 64
#define NUM_GRAPHS 64
#define NPART 8
#define PART_NODES 6250   // N_NODES / NPART exactly

typedef unsigned short u16;
typedef unsigned int u32;

__device__ __forceinline__ u16 bf16_rne(float f) {
  u32 u = __float_as_uint(f);
  u32 r = (u + 0x7fffu + ((u >> 16) & 1u)) >> 16;
  return (u16)r;
}

// ---- init: zero cnt/partial + convert x -> bf16 ----
__global__ void init_kernel(int* __restrict__ cnt, float* __restrict__ partial,
                            const float* __restrict__ x, u16* __restrict__ xh) {
  int i = blockIdx.x * blockDim.x + threadIdx.x;
  if (i < N_NODES) cnt[i] = 0;
  if (i < NUM_GRAPHS) partial[i] = 0.f;
  int stride = gridDim.x * blockDim.x;
  for (int k = i; k < N_NODES * DIM / 4; k += stride) {
    float4 v = reinterpret_cast<const float4*>(x)[k];
    ushort4 o;
    o.x = bf16_rne(v.x); o.y = bf16_rne(v.y);
    o.z = bf16_rne(v.z); o.w = bf16_rne(v.w);
    reinterpret_cast<ushort4*>(xh)[k] = o;
  }
}

// ---- pack edges to u32 (src<<16|dst) + count degrees, single pass ----
__global__ void pack_count_kernel(const int* __restrict__ src, const int* __restrict__ dst,
                                  u32* __restrict__ epk, int* __restrict__ cnt, int E) {
  int stride = gridDim.x * blockDim.x;
  for (int e = blockIdx.x * blockDim.x + threadIdx.x; e < E; e += stride) {
    int d = dst[e];
    int s = src[e];
    epk[e] = ((u32)s << 16) | (u32)d;
    atomicAdd(&cnt[d], 1);
  }
}

// ---- scan phase A ----
__global__ void scanA_kernel(const int* __restrict__ cnt, int* __restrict__ rowptr,
                             int* __restrict__ bsum, float* __restrict__ dis, int N) {
  __shared__ int wsum[16];
  int i = blockIdx.x * 1024 + threadIdx.x;
  int lane = threadIdx.x & 63, wid = threadIdx.x >> 6;
  int v = (i < N) ? cnt[i] : 0;
  if (i < N) dis[i] = rsqrtf((float)(v + 1));
  int sv = v;
  #pragma unroll
  for (int off = 1; off < 64; off <<= 1) {
    int t = __shfl_up(sv, off, 64);
    if (lane >= off) sv += t;
  }
  if (lane == 63) wsum[wid] = sv;
  __syncthreads();
  if (wid == 0) {
    int wv = (lane < 16) ? wsum[lane] : 0;
    #pragma unroll
    for (int off = 1; off < 16; off <<= 1) {
      int t = __shfl_up(wv, off, 64);
      if (lane >= off) wv += t;
    }
    if (lane < 16) wsum[lane] = wv;
  }
  __syncthreads();
  if (i < N) rowptr[i] = (wid ? wsum[wid - 1] : 0) + (sv - v);
  if (threadIdx.x == 1023) bsum[blockIdx.x] = wsum[15];
}

// ---- scan phase C (B folded in) ----
__global__ void scanC_kernel(int* __restrict__ rowptr, const int* __restrict__ bsum,
                             int* __restrict__ cursor, int nb, int N) {
  __shared__ int s_off;
  __shared__ int s_total;
  int b = blockIdx.x;
  if (threadIdx.x < 64) {
    int t = threadIdx.x;
    int v = (t < nb) ? bsum[t] : 0;
    #pragma unroll
    for (int off = 1; off < 64; off <<= 1) {
      int u = __shfl_up(v, off, 64);
      if (t >= off) v += u;
    }
    if (t == (b == 0 ? 0 : b - 1)) s_off = (b == 0) ? 0 : v;
    if (t == nb - 1) s_total = v;
  }
  __syncthreads();
  int i = b * 1024 + threadIdx.x;
  if (i < N) {
    int r = rowptr[i] + s_off;
    rowptr[i] = r;
    cursor[i] = r;
  }
  if (b == 0 && threadIdx.x == 0) rowptr[N] = s_total;
}

// ---- fill CSR, XCD-partitioned; streams 3.2MB packed edges ----
__global__ void fill_kernel(const u32* __restrict__ epk,
                            int* __restrict__ cursor, int* __restrict__ esrc, int E) {
  int p = blockIdx.x & 7;
  int lo = p * PART_NODES, hi = lo + PART_NODES;
  int stride = (gridDim.x >> 3) * blockDim.x;
  for (int e = (blockIdx.x >> 3) * blockDim.x + threadIdx.x; e < E; e += stride) {
    u32 rec = epk[e];
    int d = (int)(rec & 0xffffu);
    if (d >= lo && d < hi) {
      int pos = atomicAdd(&cursor[d], 1);
      esrc[pos] = (int)(rec >> 16);
    }
  }
}

#define UNPACK_FMA(q, d)                                              \
  a0 = fmaf(__uint_as_float((q).x << 16), (d), a0);                   \
  a1 = fmaf(__uint_as_float((q).x & 0xffff0000u), (d), a1);           \
  a2 = fmaf(__uint_as_float((q).y << 16), (d), a2);                   \
  a3 = fmaf(__uint_as_float((q).y & 0xffff0000u), (d), a3);           \
  a4 = fmaf(__uint_as_float((q).z << 16), (d), a4);                   \
  a5 = fmaf(__uint_as_float((q).z & 0xffff0000u), (d), a5);           \
  a6 = fmaf(__uint_as_float((q).w << 16), (d), a6);                   \
  a7 = fmaf(__uint_as_float((q).w & 0xffff0000u), (d), a7);

// ---- aggregate, chunk<->XCD partitioned: block partition p = blockIdx&7
// handles ONLY 16B chunk p of the bf16 feature rows. XCD p's L2 then holds
// just slice p (800KB) -> feature gathers are L2-resident. Output is
// chunk-major A_cm[8][N][8] f32 so each XCD writes a contiguous region.
// Wave layout: 4 nodes x 16 edge slots. ----
__global__ __launch_bounds__(256) void aggregate_kernel(const u16* __restrict__ Fh,
    const int* __restrict__ rowptr, const int* __restrict__ esrc,
    const float* __restrict__ dis, float* __restrict__ A_cm, int N) {
  int p = blockIdx.x & 7;                    // chunk index == XCD partition
  int wid = threadIdx.x >> 6;
  int sub = (threadIdx.x >> 4) & 3;          // node within wave
  int slot = threadIdx.x & 15;               // edge slot
  int node = (blockIdx.x >> 3) * 16 + wid * 4 + sub;
  if (node >= N) return;
  const uint4* __restrict__ F8 = reinterpret_cast<const uint4*>(Fh);
  int beg = rowptr[node], end = rowptr[node + 1];
  float a0 = 0.f, a1 = 0.f, a2 = 0.f, a3 = 0.f;
  float a4 = 0.f, a5 = 0.f, a6 = 0.f, a7 = 0.f;
  for (int j = beg + slot; j < end; j += 16) {
    int s = esrc[j];
    float d = dis[s];
    uint4 q = F8[(size_t)s * 8 + p];
    UNPACK_FMA(q, d)
  }
  // butterfly over the 16 edge slots (lane bits 0..3)
  #pragma unroll
  for (int m = 1; m < 16; m <<= 1) {
    a0 += __shfl_xor(a0, m, 64); a1 += __shfl_xor(a1, m, 64);
    a2 += __shfl_xor(a2, m, 64); a3 += __shfl_xor(a3, m, 64);
    a4 += __shfl_xor(a4, m, 64); a5 += __shfl_xor(a5, m, 64);
    a6 += __shfl_xor(a6, m, 64); a7 += __shfl_xor(a7, m, 64);
  }
  if (slot == 0) {
    float dn = dis[node];
    uint4 qs = F8[(size_t)node * 8 + p];
    float s0 = __uint_as_float(qs.x << 16), s1 = __uint_as_float(qs.x & 0xffff0000u);
    float s2 = __uint_as_float(qs.y << 16), s3 = __uint_as_float(qs.y & 0xffff0000u);
    float s4 = __uint_as_float(qs.z << 16), s5 = __uint_as_float(qs.z & 0xffff0000u);
    float s6 = __uint_as_float(qs.w << 16), s7 = __uint_as_float(qs.w & 0xffff0000u);
    float4 o0, o1;
    o0.x = (a0 + s0 * dn) * dn; o0.y = (a1 + s1 * dn) * dn;
    o0.z = (a2 + s2 * dn) * dn; o0.w = (a3 + s3 * dn) * dn;
    o1.x = (a4 + s4 * dn) * dn; o1.y = (a5 + s5 * dn) * dn;
    o1.z = (a6 + s6 * dn) * dn; o1.w = (a7 + s7 * dn) * dn;
    float4* outp = reinterpret_cast<float4*>(A_cm + ((size_t)p * N + node) * 8);
    outp[0] = o0;
    outp[1] = o1;
  }
}

// ---- fused GEMM + bias + relu; X in chunk-major A_cm[8][N][8] layout ----
__global__ __launch_bounds__(256) void gemm_bias_relu(const float* __restrict__ X,
    const float* __restrict__ W, const float* __restrict__ b,
    u16* __restrict__ Fh, int N) {
  __shared__ float4 Xs[64][16];
  int col = threadIdx.x & 63, wid = threadIdx.x >> 6;
  float wreg[DIM];
  #pragma unroll
  for (int k = 0; k < DIM; ++k) wreg[k] = W[k * DIM + col];
  float bias = b[col];
  int row0 = blockIdx.x * 64;
  const float4* __restrict__ A4 = reinterpret_cast<const float4*>(X);
  for (int i = threadIdx.x; i < 64 * 16; i += 256) {
    int r = i >> 4, c = i & 15;
    int gr = row0 + r;
    // Xs[r][c] = f32 cols 4c..4c+3 of row gr = A_cm[c>>1][gr] half (c&1)
    Xs[r][c] = (gr < N) ? A4[((size_t)(c >> 1) * N + gr) * 2 + (c & 1)]
                        : make_float4(0.f, 0.f, 0.f, 0.f);
  }
  __syncthreads();
  for (int rr = 0; rr < 16; ++rr) {
    int lr = wid * 16 + rr;
    int row = row0 + lr;
    if (row >= N) break;   // uniform per wave
    float a0 = 0.f, a1 = 0.f, a2 = 0.f, a3 = 0.f;
    #pragma unroll
    for (int kk = 0; kk < 16; ++kk) {
      float4 xv = Xs[lr][kk];
      a0 = fmaf(xv.x, wreg[4 * kk + 0], a0);
      a1 = fmaf(xv.y, wreg[4 * kk + 1], a1);
      a2 = fmaf(xv.z, wreg[4 * kk + 2], a2);
      a3 = fmaf(xv.w, wreg[4 * kk + 3], a3);
    }
    float v = fmaxf(a0 + a1 + a2 + a3 + bias, 0.f);
    Fh[(size_t)row * DIM + col] = bf16_rne(v);
  }
}

// ---- layer-3 fused: y = relu(A@W3+b3) . Wl; X in chunk-major layout ----
__global__ __launch_bounds__(256) void gemm_dot_kernel(const float* __restrict__ X,
    const float* __restrict__ W, const float* __restrict__ b, const float* __restrict__ Wl,
    const int* __restrict__ batch, float* __restrict__ partial, int N) {
  __shared__ float4 Xs[64][16];
  __shared__ float yv[64];
  __shared__ float gpart[NUM_GRAPHS];
  int col = threadIdx.x & 63, wid = threadIdx.x >> 6;
  float wreg[DIM];
  #pragma unroll
  for (int k = 0; k < DIM; ++k) wreg[k] = W[k * DIM + col];
  float bias = b[col];
  float wl = Wl[col];
  int row0 = blockIdx.x * 64;
  const float4* __restrict__ A4 = reinterpret_cast<const float4*>(X);
  if (threadIdx.x < 64) { yv[threadIdx.x] = 0.f; gpart[threadIdx.x] = 0.f; }
  for (int i = threadIdx.x; i < 64 * 16; i += 256) {
    int r = i >> 4, c = i & 15;
    int gr = row0 + r;
    Xs[r][c] = (gr < N) ? A4[((size_t)(c >> 1) * N + gr) * 2 + (c & 1)]
                        : make_float4(0.f, 0.f, 0.f, 0.f);
  }
  __syncthreads();
  for (int rr = 0; rr < 16; ++rr) {
    int lr = wid * 16 + rr;
    int row = row0 + lr;
    if (row >= N) break;   // uniform per wave
    float a0 = 0.f, a1 = 0.f, a2 = 0.f, a3 = 0.f;
    #pragma unroll
    for (int kk = 0; kk < 16; ++kk) {
      float4 xv = Xs[lr][kk];
      a0 = fmaf(xv.x, wreg[4 * kk + 0], a0);
      a1 = fmaf(xv.y, wreg[4 * kk + 1], a1);
      a2 = fmaf(xv.z, wreg[4 * kk + 2], a2);
      a3 = fmaf(xv.w, wreg[4 * kk + 3], a3);
    }
    float v = fmaxf(a0 + a1 + a2 + a3 + bias, 0.f);
    float y = v * wl;
    #pragma unroll
    for (int off = 32; off > 0; off >>= 1) y += __shfl_down(y, off, 64);
    if (col == 0) yv[lr] = y;
  }
  __syncthreads();
  if (threadIdx.x < 64) {
    int row = row0 + threadIdx.x;
    if (row < N) atomicAdd(&gpart[batch[row]], yv[threadIdx.x]);
  }
  __syncthreads();
  if (threadIdx.x < NUM_GRAPHS) {
    int glo = batch[row0];
    int ghi = batch[min(row0 + 63, N - 1)];
    int g = threadIdx.x;
    if (g >= glo && g <= ghi) atomicAdd(&partial[g], gpart[g]);
  }
}

// ---- finalize: out[g] = partial[g]/count_g + bl ----
__global__ void pool_final_kernel(const float* __restrict__ partial, const int* __restrict__ batch,
                                  const float* __restrict__ bl, float* __restrict__ out, int N) {
  int g = threadIdx.x;  // 64 threads
  int lo = 0, hi = N;
  while (lo < hi) { int m = (lo + hi) >> 1; if (batch[m] < g) lo = m + 1; else hi = m; }
  int start = lo;
  hi = N;
  while (lo < hi) { int m = (lo + hi) >> 1; if (batch[m] < g + 1) lo = m + 1; else hi = m; }
  float c = fmaxf((float)(lo - start), 1.f);
  out[g] = partial[g] / c + bl[0];
}

extern "C" void kernel_launch(void* const* d_in, const int* in_sizes, int n_in,
                              void* d_out, int out_size, void* d_ws, size_t ws_size,
                              hipStream_t stream) {
  const float* x     = (const float*)d_in[0];
  const int*   ei    = (const int*)d_in[1];   // int64 in reference, delivered as int32
  const int*   batch = (const int*)d_in[2];
  const float* W1 = (const float*)d_in[3];
  const float* b1 = (const float*)d_in[4];
  const float* W2 = (const float*)d_in[5];
  const float* b2 = (const float*)d_in[6];
  const float* W3 = (const float*)d_in[7];
  const float* b3 = (const float*)d_in[8];
  const float* Wl = (const float*)d_in[9];
  const float* bl = (const float*)d_in[10];
  float* out = (float*)d_out;

  const int* srcp = ei;
  const int* dstp = ei + N_EDGES;

  char* ws = (char*)d_ws;
  size_t off = 0;
  auto alloc = [&](size_t bytes) { void* p = ws + off; off += (bytes + 255) & ~(size_t)255; return p; };
  int*   cnt     = (int*)  alloc((size_t)N_NODES * 4);        // reused as cursor
  float* dis     = (float*)alloc((size_t)N_NODES * 4);
  int*   rowptr  = (int*)  alloc((size_t)(N_NODES + 1) * 4);
  int*   bsum    = (int*)  alloc(64 * 4);
  float* partial = (float*)alloc(NUM_GRAPHS * 4);
  u32*   epk     = (u32*)  alloc((size_t)N_EDGES * 4);
  int*   esrc    = (int*)  alloc((size_t)N_EDGES * 4);
  u16*   xh      = (u16*)  alloc((size_t)N_NODES * DIM * 2);  // bf16 feats (also layer-2 out)
  u16*   fh      = (u16*)  alloc((size_t)N_NODES * DIM * 2);  // bf16 layer-1 out
  float* A_cm    = (float*)alloc((size_t)NPART * N_NODES * 8 * 4);  // chunk-major aggregate

  const int NB = (N_NODES + 1023) / 1024;  // 49

  // ---- CSR build ----
  init_kernel<<<(N_NODES + 255) / 256, 256, 0, stream>>>(cnt, partial, x, xh);
  pack_count_kernel<<<1024, 256, 0, stream>>>(srcp, dstp, epk, cnt, N_EDGES);
  scanA_kernel<<<NB, 1024, 0, stream>>>(cnt, rowptr, bsum, dis, N_NODES);
  scanC_kernel<<<NB, 1024, 0, stream>>>(rowptr, bsum, cnt, NB, N_NODES);
  fill_kernel<<<1024, 256, 0, stream>>>(epk, cnt, esrc, N_EDGES);

  // ---- 3 GCN layers (chunk-partitioned aggregate, bf16 gathers) ----
  const int GB = (N_NODES + 63) / 64;          // 782
  const int AB = ((N_NODES + 15) / 16) * 8;    // 3125 * 8 = 25000
  aggregate_kernel<<<AB, 256, 0, stream>>>(xh, rowptr, esrc, dis, A_cm, N_NODES);
  gemm_bias_relu<<<GB, 256, 0, stream>>>(A_cm, W1, b1, fh, N_NODES);
  aggregate_kernel<<<AB, 256, 0, stream>>>(fh, rowptr, esrc, dis, A_cm, N_NODES);
  gemm_bias_relu<<<GB, 256, 0, stream>>>(A_cm, W2, b2, xh, N_NODES);   // reuse xh
  aggregate_kernel<<<AB, 256, 0, stream>>>(xh, rowptr, esrc, dis, A_cm, N_NODES);
  gemm_dot_kernel<<<GB, 256, 0, stream>>>(A_cm, W3, b3, Wl, batch, partial, N_NODES);
  pool_final_kernel<<<1, 64, 0, stream>>>(partial, batch, bl, out, N_NODES);
}

// Round 17
// 331.366 us; speedup vs baseline: 1.2166x; 1.2166x over previous
//
#include <hip/hip_runtime.h>

#define N_NODES 50000
#define N_EDGES 800000
#define DIM 64
#define NUM_GRAPHS 64
#define NPART 8
#define PART_NODES 6250   // N_NODES / NPART exactly

typedef unsigned short u16;
typedef unsigned int u32;

__device__ __forceinline__ u16 bf16_rne(float f) {
  u32 u = __float_as_uint(f);
  u32 r = (u + 0x7fffu + ((u >> 16) & 1u)) >> 16;
  return (u16)r;
}

// ---- init: zero cnt/partial + convert x -> CHUNK-MAJOR bf16 Fcm[8][N][8] ----
// chunk p of node n = columns p*8..p*8+7, stored at ((p*N)+n)*8.
__global__ void init_kernel(int* __restrict__ cnt, float* __restrict__ partial,
                            const float* __restrict__ x, u16* __restrict__ xcm) {
  int i = blockIdx.x * blockDim.x + threadIdx.x;
  if (i < N_NODES) cnt[i] = 0;
  if (i < NUM_GRAPHS) partial[i] = 0.f;
  int stride = gridDim.x * blockDim.x;
  const int total = NPART * N_NODES;
  for (int k = i; k < total; k += stride) {
    int p = k / N_NODES;
    int node = k - p * N_NODES;
    const float4* xr = reinterpret_cast<const float4*>(x + (size_t)node * DIM + p * 8);
    float4 v0 = xr[0], v1 = xr[1];
    ushort4 o0, o1;
    o0.x = bf16_rne(v0.x); o0.y = bf16_rne(v0.y);
    o0.z = bf16_rne(v0.z); o0.w = bf16_rne(v0.w);
    o1.x = bf16_rne(v1.x); o1.y = bf16_rne(v1.y);
    o1.z = bf16_rne(v1.z); o1.w = bf16_rne(v1.w);
    ushort4* outp = reinterpret_cast<ushort4*>(xcm + (size_t)k * 8);
    outp[0] = o0;
    outp[1] = o1;
  }
}

// ---- pack edges to u32 (src<<16|dst) + count degrees, single pass ----
__global__ void pack_count_kernel(const int* __restrict__ src, const int* __restrict__ dst,
                                  u32* __restrict__ epk, int* __restrict__ cnt, int E) {
  int stride = gridDim.x * blockDim.x;
  for (int e = blockIdx.x * blockDim.x + threadIdx.x; e < E; e += stride) {
    int d = dst[e];
    int s = src[e];
    epk[e] = ((u32)s << 16) | (u32)d;
    atomicAdd(&cnt[d], 1);
  }
}

// ---- scan phase A ----
__global__ void scanA_kernel(const int* __restrict__ cnt, int* __restrict__ rowptr,
                             int* __restrict__ bsum, float* __restrict__ dis, int N) {
  __shared__ int wsum[16];
  int i = blockIdx.x * 1024 + threadIdx.x;
  int lane = threadIdx.x & 63, wid = threadIdx.x >> 6;
  int v = (i < N) ? cnt[i] : 0;
  if (i < N) dis[i] = rsqrtf((float)(v + 1));
  int sv = v;
  #pragma unroll
  for (int off = 1; off < 64; off <<= 1) {
    int t = __shfl_up(sv, off, 64);
    if (lane >= off) sv += t;
  }
  if (lane == 63) wsum[wid] = sv;
  __syncthreads();
  if (wid == 0) {
    int wv = (lane < 16) ? wsum[lane] : 0;
    #pragma unroll
    for (int off = 1; off < 16; off <<= 1) {
      int t = __shfl_up(wv, off, 64);
      if (lane >= off) wv += t;
    }
    if (lane < 16) wsum[lane] = wv;
  }
  __syncthreads();
  if (i < N) rowptr[i] = (wid ? wsum[wid - 1] : 0) + (sv - v);
  if (threadIdx.x == 1023) bsum[blockIdx.x] = wsum[15];
}

// ---- scan phase C (B folded in) ----
__global__ void scanC_kernel(int* __restrict__ rowptr, const int* __restrict__ bsum,
                             int* __restrict__ cursor, int nb, int N) {
  __shared__ int s_off;
  __shared__ int s_total;
  int b = blockIdx.x;
  if (threadIdx.x < 64) {
    int t = threadIdx.x;
    int v = (t < nb) ? bsum[t] : 0;
    #pragma unroll
    for (int off = 1; off < 64; off <<= 1) {
      int u = __shfl_up(v, off, 64);
      if (t >= off) v += u;
    }
    if (t == (b == 0 ? 0 : b - 1)) s_off = (b == 0) ? 0 : v;
    if (t == nb - 1) s_total = v;
  }
  __syncthreads();
  int i = b * 1024 + threadIdx.x;
  if (i < N) {
    int r = rowptr[i] + s_off;
    rowptr[i] = r;
    cursor[i] = r;
  }
  if (b == 0 && threadIdx.x == 0) rowptr[N] = s_total;
}

// ---- fill CSR, XCD-partitioned; streams 3.2MB packed edges ----
__global__ void fill_kernel(const u32* __restrict__ epk,
                            int* __restrict__ cursor, int* __restrict__ esrc, int E) {
  int p = blockIdx.x & 7;
  int lo = p * PART_NODES, hi = lo + PART_NODES;
  int stride = (gridDim.x >> 3) * blockDim.x;
  for (int e = (blockIdx.x >> 3) * blockDim.x + threadIdx.x; e < E; e += stride) {
    u32 rec = epk[e];
    int d = (int)(rec & 0xffffu);
    if (d >= lo && d < hi) {
      int pos = atomicAdd(&cursor[d], 1);
      esrc[pos] = (int)(rec >> 16);
    }
  }
}

#define UNPACK_FMA(q, d)                                              \
  a0 = fmaf(__uint_as_float((q).x << 16), (d), a0);                   \
  a1 = fmaf(__uint_as_float((q).x & 0xffff0000u), (d), a1);           \
  a2 = fmaf(__uint_as_float((q).y << 16), (d), a2);                   \
  a3 = fmaf(__uint_as_float((q).y & 0xffff0000u), (d), a3);           \
  a4 = fmaf(__uint_as_float((q).z << 16), (d), a4);                   \
  a5 = fmaf(__uint_as_float((q).z & 0xffff0000u), (d), a5);           \
  a6 = fmaf(__uint_as_float((q).w << 16), (d), a6);                   \
  a7 = fmaf(__uint_as_float((q).w & 0xffff0000u), (d), a7);

// ---- aggregate, chunk<->XCD partitioned, CHUNK-MAJOR input Fcm[8][N][8].
// Partition p's gathers hit only its contiguous 800KB slice -> L2-resident
// on XCD p after first touch. Output chunk-major A_cm[8][N][8] f32. ----
__global__ __launch_bounds__(256) void aggregate_kernel(const u16* __restrict__ Fcm,
    const int* __restrict__ rowptr, const int* __restrict__ esrc,
    const float* __restrict__ dis, float* __restrict__ A_cm, int N) {
  int p = blockIdx.x & 7;                    // chunk index == XCD partition
  int wid = threadIdx.x >> 6;
  int sub = (threadIdx.x >> 4) & 3;          // node within wave
  int slot = threadIdx.x & 15;               // edge slot
  int node = (blockIdx.x >> 3) * 16 + wid * 4 + sub;
  if (node >= N) return;
  const uint4* __restrict__ F8 = reinterpret_cast<const uint4*>(Fcm) + (size_t)p * N;
  int beg = rowptr[node], end = rowptr[node + 1];
  float a0 = 0.f, a1 = 0.f, a2 = 0.f, a3 = 0.f;
  float a4 = 0.f, a5 = 0.f, a6 = 0.f, a7 = 0.f;
  for (int j = beg + slot; j < end; j += 16) {
    int s = esrc[j];
    float d = dis[s];
    uint4 q = F8[s];
    UNPACK_FMA(q, d)
  }
  // butterfly over the 16 edge slots (lane bits 0..3)
  #pragma unroll
  for (int m = 1; m < 16; m <<= 1) {
    a0 += __shfl_xor(a0, m, 64); a1 += __shfl_xor(a1, m, 64);
    a2 += __shfl_xor(a2, m, 64); a3 += __shfl_xor(a3, m, 64);
    a4 += __shfl_xor(a4, m, 64); a5 += __shfl_xor(a5, m, 64);
    a6 += __shfl_xor(a6, m, 64); a7 += __shfl_xor(a7, m, 64);
  }
  if (slot == 0) {
    float dn = dis[node];
    uint4 qs = F8[node];
    float s0 = __uint_as_float(qs.x << 16), s1 = __uint_as_float(qs.x & 0xffff0000u);
    float s2 = __uint_as_float(qs.y << 16), s3 = __uint_as_float(qs.y & 0xffff0000u);
    float s4 = __uint_as_float(qs.z << 16), s5 = __uint_as_float(qs.z & 0xffff0000u);
    float s6 = __uint_as_float(qs.w << 16), s7 = __uint_as_float(qs.w & 0xffff0000u);
    float4 o0, o1;
    o0.x = (a0 + s0 * dn) * dn; o0.y = (a1 + s1 * dn) * dn;
    o0.z = (a2 + s2 * dn) * dn; o0.w = (a3 + s3 * dn) * dn;
    o1.x = (a4 + s4 * dn) * dn; o1.y = (a5 + s5 * dn) * dn;
    o1.z = (a6 + s6 * dn) * dn; o1.w = (a7 + s7 * dn) * dn;
    float4* outp = reinterpret_cast<float4*>(A_cm + ((size_t)p * N + node) * 8);
    outp[0] = o0;
    outp[1] = o1;
  }
}

// ---- fused GEMM + bias + relu; A_cm input, CHUNK-MAJOR bf16 output ----
__global__ __launch_bounds__(256) void gemm_bias_relu(const float* __restrict__ X,
    const float* __restrict__ W, const float* __restrict__ b,
    u16* __restrict__ Fcm, int N) {
  __shared__ float4 Xs[64][16];
  int col = threadIdx.x & 63, wid = threadIdx.x >> 6;
  float wreg[DIM];
  #pragma unroll
  for (int k = 0; k < DIM; ++k) wreg[k] = W[k * DIM + col];
  float bias = b[col];
  int row0 = blockIdx.x * 64;
  const float4* __restrict__ A4 = reinterpret_cast<const float4*>(X);
  for (int i = threadIdx.x; i < 64 * 16; i += 256) {
    int r = i >> 4, c = i & 15;
    int gr = row0 + r;
    Xs[r][c] = (gr < N) ? A4[((size_t)(c >> 1) * N + gr) * 2 + (c & 1)]
                        : make_float4(0.f, 0.f, 0.f, 0.f);
  }
  __syncthreads();
  for (int rr = 0; rr < 16; ++rr) {
    int lr = wid * 16 + rr;
    int row = row0 + lr;
    if (row >= N) break;   // uniform per wave
    float a0 = 0.f, a1 = 0.f, a2 = 0.f, a3 = 0.f;
    #pragma unroll
    for (int kk = 0; kk < 16; ++kk) {
      float4 xv = Xs[lr][kk];
      a0 = fmaf(xv.x, wreg[4 * kk + 0], a0);
      a1 = fmaf(xv.y, wreg[4 * kk + 1], a1);
      a2 = fmaf(xv.z, wreg[4 * kk + 2], a2);
      a3 = fmaf(xv.w, wreg[4 * kk + 3], a3);
    }
    float v = fmaxf(a0 + a1 + a2 + a3 + bias, 0.f);
    Fcm[((size_t)(col >> 3) * N + row) * 8 + (col & 7)] = bf16_rne(v);
  }
}

// ---- layer-3 fused: y = relu(A@W3+b3) . Wl; A_cm input ----
__global__ __launch_bounds__(256) void gemm_dot_kernel(const float* __restrict__ X,
    const float* __restrict__ W, const float* __restrict__ b, const float* __restrict__ Wl,
    const int* __restrict__ batch, float* __restrict__ partial, int N) {
  __shared__ float4 Xs[64][16];
  __shared__ float yv[64];
  __shared__ float gpart[NUM_GRAPHS];
  int col = threadIdx.x & 63, wid = threadIdx.x >> 6;
  float wreg[DIM];
  #pragma unroll
  for (int k = 0; k < DIM; ++k) wreg[k] = W[k * DIM + col];
  float bias = b[col];
  float wl = Wl[col];
  int row0 = blockIdx.x * 64;
  const float4* __restrict__ A4 = reinterpret_cast<const float4*>(X);
  if (threadIdx.x < 64) { yv[threadIdx.x] = 0.f; gpart[threadIdx.x] = 0.f; }
  for (int i = threadIdx.x; i < 64 * 16; i += 256) {
    int r = i >> 4, c = i & 15;
    int gr = row0 + r;
    Xs[r][c] = (gr < N) ? A4[((size_t)(c >> 1) * N + gr) * 2 + (c & 1)]
                        : make_float4(0.f, 0.f, 0.f, 0.f);
  }
  __syncthreads();
  for (int rr = 0; rr < 16; ++rr) {
    int lr = wid * 16 + rr;
    int row = row0 + lr;
    if (row >= N) break;   // uniform per wave
    float a0 = 0.f, a1 = 0.f, a2 = 0.f, a3 = 0.f;
    #pragma unroll
    for (int kk = 0; kk < 16; ++kk) {
      float4 xv = Xs[lr][kk];
      a0 = fmaf(xv.x, wreg[4 * kk + 0], a0);
      a1 = fmaf(xv.y, wreg[4 * kk + 1], a1);
      a2 = fmaf(xv.z, wreg[4 * kk + 2], a2);
      a3 = fmaf(xv.w, wreg[4 * kk + 3], a3);
    }
    float v = fmaxf(a0 + a1 + a2 + a3 + bias, 0.f);
    float y = v * wl;
    #pragma unroll
    for (int off = 32; off > 0; off >>= 1) y += __shfl_down(y, off, 64);
    if (col == 0) yv[lr] = y;
  }
  __syncthreads();
  if (threadIdx.x < 64) {
    int row = row0 + threadIdx.x;
    if (row < N) atomicAdd(&gpart[batch[row]], yv[threadIdx.x]);
  }
  __syncthreads();
  if (threadIdx.x < NUM_GRAPHS) {
    int glo = batch[row0];
    int ghi = batch[min(row0 + 63, N - 1)];
    int g = threadIdx.x;
    if (g >= glo && g <= ghi) atomicAdd(&partial[g], gpart[g]);
  }
}

// ---- finalize: out[g] = partial[g]/count_g + bl ----
__global__ void pool_final_kernel(const float* __restrict__ partial, const int* __restrict__ batch,
                                  const float* __restrict__ bl, float* __restrict__ out, int N) {
  int g = threadIdx.x;  // 64 threads
  int lo = 0, hi = N;
  while (lo < hi) { int m = (lo + hi) >> 1; if (batch[m] < g) lo = m + 1; else hi = m; }
  int start = lo;
  hi = N;
  while (lo < hi) { int m = (lo + hi) >> 1; if (batch[m] < g + 1) lo = m + 1; else hi = m; }
  float c = fmaxf((float)(lo - start), 1.f);
  out[g] = partial[g] / c + bl[0];
}

extern "C" void kernel_launch(void* const* d_in, const int* in_sizes, int n_in,
                              void* d_out, int out_size, void* d_ws, size_t ws_size,
                              hipStream_t stream) {
  const float* x     = (const float*)d_in[0];
  const int*   ei    = (const int*)d_in[1];   // int64 in reference, delivered as int32
  const int*   batch = (const int*)d_in[2];
  const float* W1 = (const float*)d_in[3];
  const float* b1 = (const float*)d_in[4];
  const float* W2 = (const float*)d_in[5];
  const float* b2 = (const float*)d_in[6];
  const float* W3 = (const float*)d_in[7];
  const float* b3 = (const float*)d_in[8];
  const float* Wl = (const float*)d_in[9];
  const float* bl = (const float*)d_in[10];
  float* out = (float*)d_out;

  const int* srcp = ei;
  const int* dstp = ei + N_EDGES;

  char* ws = (char*)d_ws;
  size_t off = 0;
  auto alloc = [&](size_t bytes) { void* p = ws + off; off += (bytes + 255) & ~(size_t)255; return p; };
  int*   cnt     = (int*)  alloc((size_t)N_NODES * 4);        // reused as cursor
  float* dis     = (float*)alloc((size_t)N_NODES * 4);
  int*   rowptr  = (int*)  alloc((size_t)(N_NODES + 1) * 4);
  int*   bsum    = (int*)  alloc(64 * 4);
  float* partial = (float*)alloc(NUM_GRAPHS * 4);
  u32*   epk     = (u32*)  alloc((size_t)N_EDGES * 4);
  int*   esrc    = (int*)  alloc((size_t)N_EDGES * 4);
  u16*   xcm     = (u16*)  alloc((size_t)N_NODES * DIM * 2);  // chunk-major bf16 (also layer-2 out)
  u16*   fcm     = (u16*)  alloc((size_t)N_NODES * DIM * 2);  // chunk-major bf16 layer-1 out
  float* A_cm    = (float*)alloc((size_t)NPART * N_NODES * 8 * 4);  // chunk-major aggregate

  const int NB = (N_NODES + 1023) / 1024;  // 49

  // ---- CSR build ----
  init_kernel<<<(N_NODES + 255) / 256, 256, 0, stream>>>(cnt, partial, x, xcm);
  pack_count_kernel<<<1024, 256, 0, stream>>>(srcp, dstp, epk, cnt, N_EDGES);
  scanA_kernel<<<NB, 1024, 0, stream>>>(cnt, rowptr, bsum, dis, N_NODES);
  scanC_kernel<<<NB, 1024, 0, stream>>>(rowptr, bsum, cnt, NB, N_NODES);
  fill_kernel<<<1024, 256, 0, stream>>>(epk, cnt, esrc, N_EDGES);

  // ---- 3 GCN layers (chunk-partitioned aggregate, chunk-major bf16) ----
  const int GB = (N_NODES + 63) / 64;          // 782
  const int AB = ((N_NODES + 15) / 16) * 8;    // 25000
  aggregate_kernel<<<AB, 256, 0, stream>>>(xcm, rowptr, esrc, dis, A_cm, N_NODES);
  gemm_bias_relu<<<GB, 256, 0, stream>>>(A_cm, W1, b1, fcm, N_NODES);
  aggregate_kernel<<<AB, 256, 0, stream>>>(fcm, rowptr, esrc, dis, A_cm, N_NODES);
  gemm_bias_relu<<<GB, 256, 0, stream>>>(A_cm, W2, b2, xcm, N_NODES);   // reuse xcm
  aggregate_kernel<<<AB, 256, 0, stream>>>(xcm, rowptr, esrc, dis, A_cm, N_NODES);
  gemm_dot_kernel<<<GB, 256, 0, stream>>>(A_cm, W3, b3, Wl, batch, partial, N_NODES);
  pool_final_kernel<<<1, 64, 0, stream>>>(partial, batch, bl, out, N_NODES);
}

// Round 18
// 224.866 us; speedup vs baseline: 1.7927x; 1.4736x over previous
//
#include <hip/hip_runtime.h>

#define N_NODES 50000
#define N_EDGES 800000
#define DIM 64
#define NUM_GRAPHS 64
#define NPART 8
#define PART_NODES 6250   // N_NODES / NPART exactly

typedef unsigned short u16;
typedef unsigned int u32;

__device__ __forceinline__ u16 bf16_rne(float f) {
  u32 u = __float_as_uint(f);
  u32 r = (u + 0x7fffu + ((u >> 16) & 1u)) >> 16;
  return (u16)r;
}

// ---- init: zero cnt/partial + convert x -> bf16 ----
__global__ void init_kernel(int* __restrict__ cnt, float* __restrict__ partial,
                            const float* __restrict__ x, u16* __restrict__ xh) {
  int i = blockIdx.x * blockDim.x + threadIdx.x;
  if (i < N_NODES) cnt[i] = 0;
  if (i < NUM_GRAPHS) partial[i] = 0.f;
  int stride = gridDim.x * blockDim.x;
  for (int k = i; k < N_NODES * DIM / 4; k += stride) {
    float4 v = reinterpret_cast<const float4*>(x)[k];
    ushort4 o;
    o.x = bf16_rne(v.x); o.y = bf16_rne(v.y);
    o.z = bf16_rne(v.z); o.w = bf16_rne(v.w);
    reinterpret_cast<ushort4*>(xh)[k] = o;
  }
}

// ---- pack edges to u32 (src<<16|dst) + count degrees, single pass ----
__global__ void pack_count_kernel(const int* __restrict__ src, const int* __restrict__ dst,
                                  u32* __restrict__ epk, int* __restrict__ cnt, int E) {
  int stride = gridDim.x * blockDim.x;
  for (int e = blockIdx.x * blockDim.x + threadIdx.x; e < E; e += stride) {
    int d = dst[e];
    int s = src[e];
    epk[e] = ((u32)s << 16) | (u32)d;
    atomicAdd(&cnt[d], 1);
  }
}

// ---- scan phase A ----
__global__ void scanA_kernel(const int* __restrict__ cnt, int* __restrict__ rowptr,
                             int* __restrict__ bsum, float* __restrict__ dis, int N) {
  __shared__ int wsum[16];
  int i = blockIdx.x * 1024 + threadIdx.x;
  int lane = threadIdx.x & 63, wid = threadIdx.x >> 6;
  int v = (i < N) ? cnt[i] : 0;
  if (i < N) dis[i] = rsqrtf((float)(v + 1));
  int sv = v;
  #pragma unroll
  for (int off = 1; off < 64; off <<= 1) {
    int t = __shfl_up(sv, off, 64);
    if (lane >= off) sv += t;
  }
  if (lane == 63) wsum[wid] = sv;
  __syncthreads();
  if (wid == 0) {
    int wv = (lane < 16) ? wsum[lane] : 0;
    #pragma unroll
    for (int off = 1; off < 16; off <<= 1) {
      int t = __shfl_up(wv, off, 64);
      if (lane >= off) wv += t;
    }
    if (lane < 16) wsum[lane] = wv;
  }
  __syncthreads();
  if (i < N) rowptr[i] = (wid ? wsum[wid - 1] : 0) + (sv - v);
  if (threadIdx.x == 1023) bsum[blockIdx.x] = wsum[15];
}

// ---- scan phase C (B folded in) ----
__global__ void scanC_kernel(int* __restrict__ rowptr, const int* __restrict__ bsum,
                             int* __restrict__ cursor, int nb, int N) {
  __shared__ int s_off;
  __shared__ int s_total;
  int b = blockIdx.x;
  if (threadIdx.x < 64) {
    int t = threadIdx.x;
    int v = (t < nb) ? bsum[t] : 0;
    #pragma unroll
    for (int off = 1; off < 64; off <<= 1) {
      int u = __shfl_up(v, off, 64);
      if (t >= off) v += u;
    }
    if (t == (b == 0 ? 0 : b - 1)) s_off = (b == 0) ? 0 : v;
    if (t == nb - 1) s_total = v;
  }
  __syncthreads();
  int i = b * 1024 + threadIdx.x;
  if (i < N) {
    int r = rowptr[i] + s_off;
    rowptr[i] = r;
    cursor[i] = r;
  }
  if (b == 0 && threadIdx.x == 0) rowptr[N] = s_total;
}

// ---- fill CSR, XCD-partitioned; streams 3.2MB packed edges ----
__global__ void fill_kernel(const u32* __restrict__ epk,
                            int* __restrict__ cursor, int* __restrict__ esrc, int E) {
  int p = blockIdx.x & 7;
  int lo = p * PART_NODES, hi = lo + PART_NODES;
  int stride = (gridDim.x >> 3) * blockDim.x;
  for (int e = (blockIdx.x >> 3) * blockDim.x + threadIdx.x; e < E; e += stride) {
    u32 rec = epk[e];
    int d = (int)(rec & 0xffffu);
    if (d >= lo && d < hi) {
      int pos = atomicAdd(&cursor[d], 1);
      esrc[pos] = (int)(rec >> 16);
    }
  }
}

#define UNPACK_FMA(q, d)                                              \
  a0 = fmaf(__uint_as_float((q).x << 16), (d), a0);                   \
  a1 = fmaf(__uint_as_float((q).x & 0xffff0000u), (d), a1);           \
  a2 = fmaf(__uint_as_float((q).y << 16), (d), a2);                   \
  a3 = fmaf(__uint_as_float((q).y & 0xffff0000u), (d), a3);           \
  a4 = fmaf(__uint_as_float((q).z << 16), (d), a4);                   \
  a5 = fmaf(__uint_as_float((q).z & 0xffff0000u), (d), a5);           \
  a6 = fmaf(__uint_as_float((q).w << 16), (d), a6);                   \
  a7 = fmaf(__uint_as_float((q).w & 0xffff0000u), (d), a7);

// ---- aggregate (bf16 features): A_i = dis_i*(sum dis_j*F_j + dis_i*F_i) ----
// one wave per node; 8 lanes x 16B cover a 128B bf16 row; 8 edge slots.
// esrc for iteration i+1 is prefetched before the dependent dis/F8 gathers
// of iteration i, hiding the index-load hop of the 2-hop chain.
__global__ __launch_bounds__(256) void aggregate_kernel(const u16* __restrict__ Fh,
    const int* __restrict__ rowptr, const int* __restrict__ esrc,
    const float* __restrict__ dis, float* __restrict__ A, int N) {
  int node = blockIdx.x * 4 + (threadIdx.x >> 6);
  if (node >= N) return;
  int lane = threadIdx.x & 63;
  int qc = lane & 7;    // 16B chunk index within 128B row (8 bf16 cols)
  int qe = lane >> 3;   // edge slot 0..7
  const uint4* __restrict__ F8 = reinterpret_cast<const uint4*>(Fh);
  int beg = rowptr[node], end = rowptr[node + 1];
  float a0 = 0.f, a1 = 0.f, a2 = 0.f, a3 = 0.f;
  float a4 = 0.f, a5 = 0.f, a6 = 0.f, a7 = 0.f;
  int j = beg;
  int s0n = 0, s1n = 0;
  bool have = (j + 16 <= end);
  if (have) { s0n = esrc[j + qe]; s1n = esrc[j + 8 + qe]; }
  while (have) {
    int s0 = s0n, s1 = s1n;
    int jn = j + 16;
    bool haven = (jn + 16 <= end);
    if (haven) { s0n = esrc[jn + qe]; s1n = esrc[jn + 8 + qe]; }  // prefetch next
    float d0 = dis[s0], d1 = dis[s1];
    uint4 q0 = F8[(size_t)s0 * 8 + qc];
    uint4 q1 = F8[(size_t)s1 * 8 + qc];
    UNPACK_FMA(q0, d0)
    UNPACK_FMA(q1, d1)
    j = jn; have = haven;
  }
  if (j + 8 <= end) {
    int s0 = esrc[j + qe];
    float d0 = dis[s0];
    uint4 q0 = F8[(size_t)s0 * 8 + qc];
    UNPACK_FMA(q0, d0)
    j += 8;
  }
  if (j + qe < end) {
    int s0 = esrc[j + qe];
    float d0 = dis[s0];
    uint4 q0 = F8[(size_t)s0 * 8 + qc];
    UNPACK_FMA(q0, d0)
  }
  #pragma unroll
  for (int m = 8; m < 64; m <<= 1) {
    a0 += __shfl_xor(a0, m, 64); a1 += __shfl_xor(a1, m, 64);
    a2 += __shfl_xor(a2, m, 64); a3 += __shfl_xor(a3, m, 64);
    a4 += __shfl_xor(a4, m, 64); a5 += __shfl_xor(a5, m, 64);
    a6 += __shfl_xor(a6, m, 64); a7 += __shfl_xor(a7, m, 64);
  }
  if (qe == 0) {
    float dn = dis[node];
    uint4 qs = F8[(size_t)node * 8 + qc];
    float s0 = __uint_as_float(qs.x << 16), s1 = __uint_as_float(qs.x & 0xffff0000u);
    float s2 = __uint_as_float(qs.y << 16), s3 = __uint_as_float(qs.y & 0xffff0000u);
    float s4 = __uint_as_float(qs.z << 16), s5 = __uint_as_float(qs.z & 0xffff0000u);
    float s6 = __uint_as_float(qs.w << 16), s7 = __uint_as_float(qs.w & 0xffff0000u);
    float4 o0, o1;
    o0.x = (a0 + s0 * dn) * dn; o0.y = (a1 + s1 * dn) * dn;
    o0.z = (a2 + s2 * dn) * dn; o0.w = (a3 + s3 * dn) * dn;
    o1.x = (a4 + s4 * dn) * dn; o1.y = (a5 + s5 * dn) * dn;
    o1.z = (a6 + s6 * dn) * dn; o1.w = (a7 + s7 * dn) * dn;
    float4* A4 = reinterpret_cast<float4*>(A + (size_t)node * DIM + qc * 8);
    A4[0] = o0;
    A4[1] = o1;
  }
}

// ---- fused GEMM + bias + relu; writes bf16 for the next aggregate ----
__global__ __launch_bounds__(256) void gemm_bias_relu(const float* __restrict__ X,
    const float* __restrict__ W, const float* __restrict__ b,
    u16* __restrict__ Fh, int N) {
  __shared__ float4 Xs[64][16];
  int col = threadIdx.x & 63, wid = threadIdx.x >> 6;
  float wreg[DIM];
  #pragma unroll
  for (int k = 0; k < DIM; ++k) wreg[k] = W[k * DIM + col];
  float bias = b[col];
  int row0 = blockIdx.x * 64;
  for (int i = threadIdx.x; i < 64 * 16; i += 256) {
    int r = i >> 4, c = i & 15;
    int gr = row0 + r;
    Xs[r][c] = (gr < N) ? reinterpret_cast<const float4*>(X)[(size_t)gr * 16 + c]
                        : make_float4(0.f, 0.f, 0.f, 0.f);
  }
  __syncthreads();
  for (int rr = 0; rr < 16; ++rr) {
    int lr = wid * 16 + rr;
    int row = row0 + lr;
    if (row >= N) break;   // uniform per wave
    float a0 = 0.f, a1 = 0.f, a2 = 0.f, a3 = 0.f;
    #pragma unroll
    for (int kk = 0; kk < 16; ++kk) {
      float4 xv = Xs[lr][kk];
      a0 = fmaf(xv.x, wreg[4 * kk + 0], a0);
      a1 = fmaf(xv.y, wreg[4 * kk + 1], a1);
      a2 = fmaf(xv.z, wreg[4 * kk + 2], a2);
      a3 = fmaf(xv.w, wreg[4 * kk + 3], a3);
    }
    float v = fmaxf(a0 + a1 + a2 + a3 + bias, 0.f);
    Fh[(size_t)row * DIM + col] = bf16_rne(v);
  }
}

// ---- layer-3 fused: y = relu(A@W3+b3) . Wl, block-level graph partials ----
__global__ __launch_bounds__(256) void gemm_dot_kernel(const float* __restrict__ X,
    const float* __restrict__ W, const float* __restrict__ b, const float* __restrict__ Wl,
    const int* __restrict__ batch, float* __restrict__ partial, int N) {
  __shared__ float4 Xs[64][16];
  __shared__ float yv[64];
  __shared__ float gpart[NUM_GRAPHS];
  int col = threadIdx.x & 63, wid = threadIdx.x >> 6;
  float wreg[DIM];
  #pragma unroll
  for (int k = 0; k < DIM; ++k) wreg[k] = W[k * DIM + col];
  float bias = b[col];
  float wl = Wl[col];
  int row0 = blockIdx.x * 64;
  if (threadIdx.x < 64) { yv[threadIdx.x] = 0.f; gpart[threadIdx.x] = 0.f; }
  for (int i = threadIdx.x; i < 64 * 16; i += 256) {
    int r = i >> 4, c = i & 15;
    int gr = row0 + r;
    Xs[r][c] = (gr < N) ? reinterpret_cast<const float4*>(X)[(size_t)gr * 16 + c]
                        : make_float4(0.f, 0.f, 0.f, 0.f);
  }
  __syncthreads();
  for (int rr = 0; rr < 16; ++rr) {
    int lr = wid * 16 + rr;
    int row = row0 + lr;
    if (row >= N) break;   // uniform per wave
    float a0 = 0.f, a1 = 0.f, a2 = 0.f, a3 = 0.f;
    #pragma unroll
    for (int kk = 0; kk < 16; ++kk) {
      float4 xv = Xs[lr][kk];
      a0 = fmaf(xv.x, wreg[4 * kk + 0], a0);
      a1 = fmaf(xv.y, wreg[4 * kk + 1], a1);
      a2 = fmaf(xv.z, wreg[4 * kk + 2], a2);
      a3 = fmaf(xv.w, wreg[4 * kk + 3], a3);
    }
    float v = fmaxf(a0 + a1 + a2 + a3 + bias, 0.f);
    float y = v * wl;
    #pragma unroll
    for (int off = 32; off > 0; off >>= 1) y += __shfl_down(y, off, 64);
    if (col == 0) yv[lr] = y;
  }
  __syncthreads();
  if (threadIdx.x < 64) {
    int row = row0 + threadIdx.x;
    if (row < N) atomicAdd(&gpart[batch[row]], yv[threadIdx.x]);
  }
  __syncthreads();
  if (threadIdx.x < NUM_GRAPHS) {
    int glo = batch[row0];
    int ghi = batch[min(row0 + 63, N - 1)];
    int g = threadIdx.x;
    if (g >= glo && g <= ghi) atomicAdd(&partial[g], gpart[g]);
  }
}

// ---- finalize: out[g] = partial[g]/count_g + bl ----
__global__ void pool_final_kernel(const float* __restrict__ partial, const int* __restrict__ batch,
                                  const float* __restrict__ bl, float* __restrict__ out, int N) {
  int g = threadIdx.x;  // 64 threads
  int lo = 0, hi = N;
  while (lo < hi) { int m = (lo + hi) >> 1; if (batch[m] < g) lo = m + 1; else hi = m; }
  int start = lo;
  hi = N;
  while (lo < hi) { int m = (lo + hi) >> 1; if (batch[m] < g + 1) lo = m + 1; else hi = m; }
  float c = fmaxf((float)(lo - start), 1.f);
  out[g] = partial[g] / c + bl[0];
}

extern "C" void kernel_launch(void* const* d_in, const int* in_sizes, int n_in,
                              void* d_out, int out_size, void* d_ws, size_t ws_size,
                              hipStream_t stream) {
  const float* x     = (const float*)d_in[0];
  const int*   ei    = (const int*)d_in[1];   // int64 in reference, delivered as int32
  const int*   batch = (const int*)d_in[2];
  const float* W1 = (const float*)d_in[3];
  const float* b1 = (const float*)d_in[4];
  const float* W2 = (const float*)d_in[5];
  const float* b2 = (const float*)d_in[6];
  const float* W3 = (const float*)d_in[7];
  const float* b3 = (const float*)d_in[8];
  const float* Wl = (const float*)d_in[9];
  const float* bl = (const float*)d_in[10];
  float* out = (float*)d_out;

  const int* srcp = ei;
  const int* dstp = ei + N_EDGES;

  char* ws = (char*)d_ws;
  size_t off = 0;
  auto alloc = [&](size_t bytes) { void* p = ws + off; off += (bytes + 255) & ~(size_t)255; return p; };
  int*   cnt     = (int*)  alloc((size_t)N_NODES * 4);        // reused as cursor
  float* dis     = (float*)alloc((size_t)N_NODES * 4);
  int*   rowptr  = (int*)  alloc((size_t)(N_NODES + 1) * 4);
  int*   bsum    = (int*)  alloc(64 * 4);
  float* partial = (float*)alloc(NUM_GRAPHS * 4);
  u32*   epk     = (u32*)  alloc((size_t)N_EDGES * 4);
  int*   esrc    = (int*)  alloc((size_t)N_EDGES * 4);
  u16*   xh      = (u16*)  alloc((size_t)N_NODES * DIM * 2);  // bf16 feats (also layer-2 out)
  u16*   fh      = (u16*)  alloc((size_t)N_NODES * DIM * 2);  // bf16 layer-1 out
  float* A       = (float*)alloc((size_t)N_NODES * DIM * 4);  // f32 aggregate output

  const int NB = (N_NODES + 1023) / 1024;  // 49

  // ---- CSR build ----
  init_kernel<<<(N_NODES + 255) / 256, 256, 0, stream>>>(cnt, partial, x, xh);
  pack_count_kernel<<<1024, 256, 0, stream>>>(srcp, dstp, epk, cnt, N_EDGES);
  scanA_kernel<<<NB, 1024, 0, stream>>>(cnt, rowptr, bsum, dis, N_NODES);
  scanC_kernel<<<NB, 1024, 0, stream>>>(rowptr, bsum, cnt, NB, N_NODES);
  fill_kernel<<<1024, 256, 0, stream>>>(epk, cnt, esrc, N_EDGES);

  // ---- 3 GCN layers (bf16 gathers, f32 accumulate/GEMM) ----
  const int GB = (N_NODES + 63) / 64;  // 782
  const int AB = (N_NODES + 3) / 4;
  aggregate_kernel<<<AB, 256, 0, stream>>>(xh, rowptr, esrc, dis, A, N_NODES);
  gemm_bias_relu<<<GB, 256, 0, stream>>>(A, W1, b1, fh, N_NODES);
  aggregate_kernel<<<AB, 256, 0, stream>>>(fh, rowptr, esrc, dis, A, N_NODES);
  gemm_bias_relu<<<GB, 256, 0, stream>>>(A, W2, b2, xh, N_NODES);   // reuse xh
  aggregate_kernel<<<AB, 256, 0, stream>>>(xh, rowptr, esrc, dis, A, N_NODES);
  gemm_dot_kernel<<<GB, 256, 0, stream>>>(A, W3, b3, Wl, batch, partial, N_NODES);
  pool_final_kernel<<<1, 64, 0, stream>>>(partial, batch, bl, out, N_NODES);
}